// Round 2
// baseline (115.490 us; speedup 1.0000x reference)
//
#include <hip/hip_runtime.h>

#define NN 2048
#define DD 128
#define HH 64

// ---------------- Kernel 1: projections ----------------
// pi[i][h]  = agent[i] . W1a[:,h]
// pjt[j][h] = agent[j] . W1b[:,h] + (task . W1c[:,h] + b1[h])
__global__ __launch_bounds__(256) void proj_kernel(
    const float* __restrict__ z, const float* __restrict__ W1,
    const float* __restrict__ b1, float* __restrict__ pi, float* __restrict__ pjt)
{
    __shared__ float sA[16][DD];
    __shared__ float sT[DD];
    const int t = threadIdx.x;
    const int rowBase = blockIdx.x * 16;

    #pragma unroll
    for (int c = 0; c < 2; ++c) {
        int idx = c * 256 + t;          // float4 index 0..511
        int rr  = idx >> 5;             // 32 float4 per row
        int kq  = idx & 31;
        float4 v = *(const float4*)(z + (rowBase + rr) * DD + kq * 4);
        *(float4*)(&sA[rr][kq * 4]) = v;
    }
    if (t < DD / 4) {
        float4 v = *(const float4*)(z + (size_t)NN * DD + t * 4);  // task row
        *(float4*)(&sT[t * 4]) = v;
    }
    __syncthreads();

    const int h  = t & 63;
    const int rg = t >> 6;              // wave-uniform -> sA reads broadcast

    float ai[4] = {0.f, 0.f, 0.f, 0.f};
    float aj[4] = {0.f, 0.f, 0.f, 0.f};
    float at = 0.f;
    #pragma unroll 4
    for (int k = 0; k < DD; ++k) {
        const float w1a = W1[k * HH + h];
        const float w1b = W1[(DD + k) * HH + h];
        const float w1c = W1[(2 * DD + k) * HH + h];
        at = fmaf(sT[k], w1c, at);
        #pragma unroll
        for (int a = 0; a < 4; ++a) {
            const float av = sA[rg * 4 + a][k];
            ai[a] = fmaf(av, w1a, ai[a]);
            aj[a] = fmaf(av, w1b, aj[a]);
        }
    }
    const float ptv = at + b1[h];
    #pragma unroll
    for (int a = 0; a < 4; ++a) {
        const int row = rowBase + rg * 4 + a;
        pi[row * HH + h]  = ai[a];
        pjt[row * HH + h] = aj[a] + ptv;
    }
}

// ---------------- Kernel 2: pairwise decode ----------------
// out[i][j] = e/(e+(1-e)*exp(-w)), w = sum_h relu(pi[i][h]+pjt[j][h])*W2[h] + b2
// Block tile 128(i) x 64(j), 256 threads, thread tile 8x4, grid (32,16) = 512
// blocks -> 2 blocks/CU so staging/epilogue of one overlaps compute of other.
// LDS layout [h][i] transposed, stride 132/68 (16B aligned, no >2-way bank
// aliasing in main-loop reads). eps prefetched to registers before h-loop.
__global__ __launch_bounds__(256, 2) void pair_kernel(
    const float* __restrict__ pi, const float* __restrict__ pjt,
    const float* __restrict__ W2, const float* __restrict__ b2,
    const float* __restrict__ eps, float* __restrict__ out)
{
    __shared__ float sPi[HH][132];   // [h][i 0..127]
    __shared__ float sPj[HH][68];    // [h][j 0..63]

    const int t  = threadIdx.x;
    const int i0 = blockIdx.y * 128;
    const int j0 = blockIdx.x * 64;

    // ---- stage pi: 128 rows x 64 h, transposed via in-register 4x4 ----
    #pragma unroll
    for (int c = 0; c < 2; ++c) {
        const int g  = c * 256 + t;     // 0..511
        const int hq = g & 15;          // h quad
        const int ig = g >> 4;          // i group of 4 rows (0..31)
        const float* src = pi + (size_t)(i0 + ig * 4) * HH + hq * 4;
        float4 v0 = *(const float4*)(src);
        float4 v1 = *(const float4*)(src + HH);
        float4 v2 = *(const float4*)(src + 2 * HH);
        float4 v3 = *(const float4*)(src + 3 * HH);
        *(float4*)(&sPi[hq * 4 + 0][ig * 4]) = make_float4(v0.x, v1.x, v2.x, v3.x);
        *(float4*)(&sPi[hq * 4 + 1][ig * 4]) = make_float4(v0.y, v1.y, v2.y, v3.y);
        *(float4*)(&sPi[hq * 4 + 2][ig * 4]) = make_float4(v0.z, v1.z, v2.z, v3.z);
        *(float4*)(&sPi[hq * 4 + 3][ig * 4]) = make_float4(v0.w, v1.w, v2.w, v3.w);
    }
    // ---- stage pjt: 64 rows x 64 h ----
    {
        const int hq = t & 15;
        const int jg = t >> 4;          // 0..15
        const float* src = pjt + (size_t)(j0 + jg * 4) * HH + hq * 4;
        float4 v0 = *(const float4*)(src);
        float4 v1 = *(const float4*)(src + HH);
        float4 v2 = *(const float4*)(src + 2 * HH);
        float4 v3 = *(const float4*)(src + 3 * HH);
        *(float4*)(&sPj[hq * 4 + 0][jg * 4]) = make_float4(v0.x, v1.x, v2.x, v3.x);
        *(float4*)(&sPj[hq * 4 + 1][jg * 4]) = make_float4(v0.y, v1.y, v2.y, v3.y);
        *(float4*)(&sPj[hq * 4 + 2][jg * 4]) = make_float4(v0.z, v1.z, v2.z, v3.z);
        *(float4*)(&sPj[hq * 4 + 3][jg * 4]) = make_float4(v0.w, v1.w, v2.w, v3.w);
    }

    const int lane = t & 63;
    const int wv   = t >> 6;
    const int ib   = (wv >> 1) * 64 + (lane >> 3) * 8;  // thread's 8 i's
    const int jb   = (wv & 1) * 32 + (lane & 7) * 4;    // thread's 4 j's

    // ---- prefetch eps (8 x float4) so HBM latency hides under the h-loop ----
    float4 eps4[8];
    #pragma unroll
    for (int r = 0; r < 8; ++r)
        eps4[r] = *(const float4*)(eps + (size_t)(i0 + ib + r) * NN + (j0 + jb));

    __syncthreads();

    float acc[8][4];
    #pragma unroll
    for (int r = 0; r < 8; ++r)
        #pragma unroll
        for (int c = 0; c < 4; ++c) acc[r][c] = 0.f;

    #pragma unroll 4
    for (int h = 0; h < HH; ++h) {
        const float4 a0 = *(const float4*)(&sPi[h][ib]);
        const float4 a1 = *(const float4*)(&sPi[h][ib + 4]);
        const float4 bv = *(const float4*)(&sPj[h][jb]);
        const float w2h = W2[h];                 // wave-uniform -> s_load
        const float ai[8] = {a0.x, a0.y, a0.z, a0.w, a1.x, a1.y, a1.z, a1.w};
        const float bj[4] = {bv.x, bv.y, bv.z, bv.w};
        #pragma unroll
        for (int r = 0; r < 8; ++r)
            #pragma unroll
            for (int c = 0; c < 4; ++c)
                acc[r][c] = fmaf(fmaxf(ai[r] + bj[c], 0.f), w2h, acc[r][c]);
    }

    const float b2v = b2[0];
    #pragma unroll
    for (int r = 0; r < 8; ++r) {
        const size_t base = (size_t)(i0 + ib + r) * NN + (j0 + jb);
        const float4 e4 = eps4[r];
        float4 o;
        {
            float e = e4.x + 1e-8f, w = acc[r][0] + b2v;
            o.x = __fdividef(e, e + (1.f - e) * __expf(-w));
        }
        {
            float e = e4.y + 1e-8f, w = acc[r][1] + b2v;
            o.y = __fdividef(e, e + (1.f - e) * __expf(-w));
        }
        {
            float e = e4.z + 1e-8f, w = acc[r][2] + b2v;
            o.z = __fdividef(e, e + (1.f - e) * __expf(-w));
        }
        {
            float e = e4.w + 1e-8f, w = acc[r][3] + b2v;
            o.w = __fdividef(e, e + (1.f - e) * __expf(-w));
        }
        *(float4*)(out + base) = o;
    }
}

extern "C" void kernel_launch(void* const* d_in, const int* in_sizes, int n_in,
                              void* d_out, int out_size, void* d_ws, size_t ws_size,
                              hipStream_t stream) {
    const float* z   = (const float*)d_in[0];   // (2049,128)
    const float* W1  = (const float*)d_in[1];   // (384,64)
    const float* b1  = (const float*)d_in[2];   // (64,)
    const float* W2  = (const float*)d_in[3];   // (64,1)
    const float* b2  = (const float*)d_in[4];   // (1,)
    const float* eps = (const float*)d_in[5];   // (2048,2048)
    float* out = (float*)d_out;                 // (2048,2048) fp32

    float* pi  = (float*)d_ws;                  // N*H floats
    float* pjt = pi + (size_t)NN * HH;          // N*H floats

    proj_kernel<<<NN / 16, 256, 0, stream>>>(z, W1, b1, pi, pjt);
    pair_kernel<<<dim3(NN / 64, NN / 128), 256, 0, stream>>>(pi, pjt, W2, b2, eps, out);
}

// Round 3
// 109.979 us; speedup vs baseline: 1.0501x; 1.0501x over previous
//
#include <hip/hip_runtime.h>

#define NN 2048
#define DD 128
#define HH 64

typedef _Float16 half2v __attribute__((ext_vector_type(2)));

static __device__ __forceinline__ unsigned pack_h2(float x, float y) {
    half2v v;
    v.x = (_Float16)x;
    v.y = (_Float16)y;
    return __builtin_bit_cast(unsigned, v);
}
static __device__ __forceinline__ half2v unpack_h2(unsigned u) {
    return __builtin_bit_cast(half2v, u);
}

// ---------------- Kernel 1: projections (f16 h-pair packed output) ---------
// piH[i][h2]  = pack(agent[i].W1a[:,2h2], agent[i].W1a[:,2h2+1])
// pjtH[j][h2] = pack of agent[j].W1b + (task.W1c + b1), h-pair packed.
// Also writes w2pair[h2] = pack(W2[2h2], W2[2h2+1]) (block 0).
__global__ __launch_bounds__(256) void proj_kernel(
    const float* __restrict__ z, const float* __restrict__ W1,
    const float* __restrict__ b1, const float* __restrict__ W2,
    unsigned* __restrict__ piH, unsigned* __restrict__ pjtH,
    unsigned* __restrict__ w2pair)
{
    __shared__ float sA[16][DD];
    __shared__ float sT[DD];
    const int t = threadIdx.x;
    const int rowBase = blockIdx.x * 16;

    #pragma unroll
    for (int c = 0; c < 2; ++c) {
        int idx = c * 256 + t;          // float4 index 0..511
        int rr  = idx >> 5;             // 32 float4 per row
        int kq  = idx & 31;
        float4 v = *(const float4*)(z + (rowBase + rr) * DD + kq * 4);
        *(float4*)(&sA[rr][kq * 4]) = v;
    }
    if (t < DD / 4) {
        float4 v = *(const float4*)(z + (size_t)NN * DD + t * 4);  // task row
        *(float4*)(&sT[t * 4]) = v;
    }
    if (blockIdx.x == 0 && t < HH / 2)
        w2pair[t] = pack_h2(W2[2 * t], W2[2 * t + 1]);
    __syncthreads();

    const int h2 = t & 31;              // h-pair 0..31 (coalesced float2 W1 loads)
    const int rg = t >> 5;              // 0..7 -> rows rg*2, rg*2+1

    float ai[2][2] = {{0.f,0.f},{0.f,0.f}};
    float aj[2][2] = {{0.f,0.f},{0.f,0.f}};
    float at[2] = {0.f, 0.f};
    #pragma unroll 4
    for (int k = 0; k < DD; ++k) {
        const float2 wa = *(const float2*)(W1 + (size_t)k * HH + 2 * h2);
        const float2 wb = *(const float2*)(W1 + (size_t)(DD + k) * HH + 2 * h2);
        const float2 wc = *(const float2*)(W1 + (size_t)(2 * DD + k) * HH + 2 * h2);
        const float tv = sT[k];
        at[0] = fmaf(tv, wc.x, at[0]);
        at[1] = fmaf(tv, wc.y, at[1]);
        #pragma unroll
        for (int r = 0; r < 2; ++r) {
            const float av = sA[rg * 2 + r][k];
            ai[r][0] = fmaf(av, wa.x, ai[r][0]);
            ai[r][1] = fmaf(av, wa.y, ai[r][1]);
            aj[r][0] = fmaf(av, wb.x, aj[r][0]);
            aj[r][1] = fmaf(av, wb.y, aj[r][1]);
        }
    }
    const float pt0 = at[0] + b1[2 * h2];
    const float pt1 = at[1] + b1[2 * h2 + 1];
    #pragma unroll
    for (int r = 0; r < 2; ++r) {
        const int row = rowBase + rg * 2 + r;
        piH [row * (HH/2) + h2] = pack_h2(ai[r][0], ai[r][1]);
        pjtH[row * (HH/2) + h2] = pack_h2(aj[r][0] + pt0, aj[r][1] + pt1);
    }
}

// ---------------- Kernel 2: pairwise decode (f16 dot2 inner loop) ----------
// out[i][j] = e/(e+(1-e)*exp(-w)), w = sum_h relu(pi[i][h]+pjt[j][h])*W2[h]+b2
// Block tile 128(i) x 64(j), 256 threads, thread tile 8x4, grid 512 = 2
// blocks/CU. LDS [h2][i] transposed (strides 132/68: 16B aligned, <=2-way
// bank aliasing in main loop = free). Inner: v_pk_add_f16 + v_pk_max_f16 +
// v_dot2_f32_f16 per h-PAIR -> 1.5 VALU ops per output per h (was 3).
__global__ __launch_bounds__(256, 2) void pair_kernel(
    const unsigned* __restrict__ piH, const unsigned* __restrict__ pjtH,
    const unsigned* __restrict__ w2pair, const float* __restrict__ b2,
    const float* __restrict__ eps, float* __restrict__ out)
{
    __shared__ unsigned sPi[HH/2][132];   // [h2][i 0..127]
    __shared__ unsigned sPj[HH/2][68];    // [h2][j 0..63]

    const int t  = threadIdx.x;
    const int i0 = blockIdx.y * 128;
    const int j0 = blockIdx.x * 64;

    // ---- stage piH: 128 rows x 32 h2, transposed via in-register 4x4 ----
    {
        const int ig = t & 31;          // i group of 4 rows
        const int hq = t >> 5;          // h2 quad 0..7
        const unsigned* src = piH + (size_t)(i0 + ig * 4) * (HH/2) + hq * 4;
        uint4 v0 = *(const uint4*)(src);
        uint4 v1 = *(const uint4*)(src + (HH/2));
        uint4 v2 = *(const uint4*)(src + 2 * (HH/2));
        uint4 v3 = *(const uint4*)(src + 3 * (HH/2));
        *(uint4*)(&sPi[hq * 4 + 0][ig * 4]) = make_uint4(v0.x, v1.x, v2.x, v3.x);
        *(uint4*)(&sPi[hq * 4 + 1][ig * 4]) = make_uint4(v0.y, v1.y, v2.y, v3.y);
        *(uint4*)(&sPi[hq * 4 + 2][ig * 4]) = make_uint4(v0.z, v1.z, v2.z, v3.z);
        *(uint4*)(&sPi[hq * 4 + 3][ig * 4]) = make_uint4(v0.w, v1.w, v2.w, v3.w);
    }
    // ---- stage pjtH: 64 rows x 32 h2 (threads 0..127) ----
    if (t < 128) {
        const int jg = t & 15;
        const int hq = t >> 4;
        const unsigned* src = pjtH + (size_t)(j0 + jg * 4) * (HH/2) + hq * 4;
        uint4 v0 = *(const uint4*)(src);
        uint4 v1 = *(const uint4*)(src + (HH/2));
        uint4 v2 = *(const uint4*)(src + 2 * (HH/2));
        uint4 v3 = *(const uint4*)(src + 3 * (HH/2));
        *(uint4*)(&sPj[hq * 4 + 0][jg * 4]) = make_uint4(v0.x, v1.x, v2.x, v3.x);
        *(uint4*)(&sPj[hq * 4 + 1][jg * 4]) = make_uint4(v0.y, v1.y, v2.y, v3.y);
        *(uint4*)(&sPj[hq * 4 + 2][jg * 4]) = make_uint4(v0.z, v1.z, v2.z, v3.z);
        *(uint4*)(&sPj[hq * 4 + 3][jg * 4]) = make_uint4(v0.w, v1.w, v2.w, v3.w);
    }

    const int lane = t & 63;
    const int wv   = t >> 6;
    const int ib   = (wv >> 1) * 64 + (lane >> 3) * 8;  // thread's 8 i's
    const int jb   = (wv & 1) * 32 + (lane & 7) * 4;    // thread's 4 j's

    // ---- prefetch eps (8 x float4): HBM latency hides under the h-loop ----
    float4 eps4[8];
    #pragma unroll
    for (int r = 0; r < 8; ++r)
        eps4[r] = *(const float4*)(eps + (size_t)(i0 + ib + r) * NN + (j0 + jb));

    __syncthreads();

    float acc[8][4];
    #pragma unroll
    for (int r = 0; r < 8; ++r)
        #pragma unroll
        for (int c = 0; c < 4; ++c) acc[r][c] = 0.f;

    const half2v hz = (half2v)(_Float16)0;

    #pragma unroll 4
    for (int h2 = 0; h2 < HH / 2; ++h2) {
        const uint4 A0 = *(const uint4*)(&sPi[h2][ib]);
        const uint4 A1 = *(const uint4*)(&sPi[h2][ib + 4]);
        const uint4 B  = *(const uint4*)(&sPj[h2][jb]);
        const unsigned w2u = w2pair[h2];            // uniform -> s_load
        const half2v w2h = unpack_h2(w2u);
        const unsigned au[8] = {A0.x, A0.y, A0.z, A0.w, A1.x, A1.y, A1.z, A1.w};
        const unsigned bu[4] = {B.x, B.y, B.z, B.w};
        #pragma unroll
        for (int r = 0; r < 8; ++r) {
            const half2v ah = unpack_h2(au[r]);
            #pragma unroll
            for (int c = 0; c < 4; ++c) {
                half2v s = ah + unpack_h2(bu[c]);               // v_pk_add_f16
                s = __builtin_elementwise_max(s, hz);           // v_pk_max_f16
#if __has_builtin(__builtin_amdgcn_fdot2)
                acc[r][c] = __builtin_amdgcn_fdot2(s, w2h, acc[r][c], false);
#else
                acc[r][c] = fmaf((float)s.x, (float)w2h.x,
                            fmaf((float)s.y, (float)w2h.y, acc[r][c]));
#endif
            }
        }
    }

    const float b2v = b2[0];
    #pragma unroll
    for (int r = 0; r < 8; ++r) {
        const size_t base = (size_t)(i0 + ib + r) * NN + (j0 + jb);
        const float4 e4 = eps4[r];
        float4 o;
        {
            float e = e4.x + 1e-8f, w = acc[r][0] + b2v;
            o.x = __fdividef(e, e + (1.f - e) * __expf(-w));
        }
        {
            float e = e4.y + 1e-8f, w = acc[r][1] + b2v;
            o.y = __fdividef(e, e + (1.f - e) * __expf(-w));
        }
        {
            float e = e4.z + 1e-8f, w = acc[r][2] + b2v;
            o.z = __fdividef(e, e + (1.f - e) * __expf(-w));
        }
        {
            float e = e4.w + 1e-8f, w = acc[r][3] + b2v;
            o.w = __fdividef(e, e + (1.f - e) * __expf(-w));
        }
        *(float4*)(out + base) = o;
    }
}

extern "C" void kernel_launch(void* const* d_in, const int* in_sizes, int n_in,
                              void* d_out, int out_size, void* d_ws, size_t ws_size,
                              hipStream_t stream) {
    const float* z   = (const float*)d_in[0];   // (2049,128)
    const float* W1  = (const float*)d_in[1];   // (384,64)
    const float* b1  = (const float*)d_in[2];   // (64,)
    const float* W2  = (const float*)d_in[3];   // (64,1)
    const float* b2  = (const float*)d_in[4];   // (1,)
    const float* eps = (const float*)d_in[5];   // (2048,2048)
    float* out = (float*)d_out;                 // (2048,2048) fp32

    unsigned* piH    = (unsigned*)d_ws;                    // N*32 uints (256KB)
    unsigned* pjtH   = piH + (size_t)NN * (HH / 2);        // N*32 uints (256KB)
    unsigned* w2pair = pjtH + (size_t)NN * (HH / 2);       // 32 uints

    proj_kernel<<<NN / 16, 256, 0, stream>>>(z, W1, b1, W2, piH, pjtH, w2pair);
    pair_kernel<<<dim3(NN / 64, NN / 128), 256, 0, stream>>>(piH, pjtH, w2pair, b2, eps, out);
}